// Round 1
// baseline (17302.090 us; speedup 1.0000x reference)
//
#include <hip/hip_runtime.h>
#include <hip/hip_bf16.h>
#include <math.h>

// Problem constants
constexpr int Bb  = 4;
constexpr int Tt  = 2048;
constexpr int DM  = 1024;
constexpr int NH  = 16;
constexpr int HD  = 64;
constexpr int MBT = Bb * Tt;          // 8192 rows
constexpr float LOG_THETA = 9.210340371976184f;   // ln(10000)

// ---------------------------------------------------------------------------
// Kernel 1: QKV GEMM (M=8192, N=3072, K=1024), C = X * W^T, fused RoPE,
// scatter to Q/K/V in [B][H][T][64] layout.
// Tile 64x64, BK=16, 256 threads, 4x4 micro-tile per thread.
// ---------------------------------------------------------------------------
__global__ __launch_bounds__(256) void gemm_qkv_rope(
    const float* __restrict__ X, const float* __restrict__ W,
    float* __restrict__ Qo, float* __restrict__ Ko, float* __restrict__ Vo)
{
    __shared__ float As[16][65];
    __shared__ float Bs[16][65];
    const int tid = threadIdx.x;
    const int bm  = blockIdx.y * 64;
    const int bn  = blockIdx.x * 64;
    const int tx  = tid & 15;
    const int ty  = tid >> 4;
    const int lm  = tid >> 2;        // 0..63 (row within tile for loads)
    const int lk  = (tid & 3) * 4;   // 0,4,8,12

    float c[4][4] = {};

    const float* xp = X + (size_t)(bm + lm) * 1024 + lk;
    const float* wp = W + (size_t)(bn + lm) * 1024 + lk;

    for (int k0 = 0; k0 < 1024; k0 += 16) {
        float4 av = *reinterpret_cast<const float4*>(xp + k0);
        float4 bv = *reinterpret_cast<const float4*>(wp + k0);
        As[lk + 0][lm] = av.x; As[lk + 1][lm] = av.y;
        As[lk + 2][lm] = av.z; As[lk + 3][lm] = av.w;
        Bs[lk + 0][lm] = bv.x; Bs[lk + 1][lm] = bv.y;
        Bs[lk + 2][lm] = bv.z; Bs[lk + 3][lm] = bv.w;
        __syncthreads();
        #pragma unroll
        for (int k = 0; k < 16; ++k) {
            float a0 = As[k][ty * 4 + 0], a1 = As[k][ty * 4 + 1];
            float a2 = As[k][ty * 4 + 2], a3 = As[k][ty * 4 + 3];
            float b0 = Bs[k][tx * 4 + 0], b1 = Bs[k][tx * 4 + 1];
            float b2 = Bs[k][tx * 4 + 2], b3 = Bs[k][tx * 4 + 3];
            c[0][0] += a0 * b0; c[0][1] += a0 * b1; c[0][2] += a0 * b2; c[0][3] += a0 * b3;
            c[1][0] += a1 * b0; c[1][1] += a1 * b1; c[1][2] += a1 * b2; c[1][3] += a1 * b3;
            c[2][0] += a2 * b0; c[2][1] += a2 * b1; c[2][2] += a2 * b2; c[2][3] += a2 * b3;
            c[3][0] += a3 * b0; c[3][1] += a3 * b1; c[3][2] += a3 * b2; c[3][3] += a3 * b3;
        }
        __syncthreads();
    }

    // Epilogue: RoPE for q/k sections, plain for v; scatter to [B][H][T][64].
    #pragma unroll
    for (int i = 0; i < 4; ++i) {
        int row = bm + ty * 4 + i;
        int b_  = row >> 11;       // / 2048
        int t_  = row & 2047;
        #pragma unroll
        for (int jp = 0; jp < 2; ++jp) {
            int o0   = bn + tx * 4 + jp * 2;   // even output column
            int sect = o0 >> 10;               // 0=q, 1=k, 2=v
            int rem  = o0 & 1023;
            int h    = rem >> 6;
            int d    = rem & 63;               // even
            float v0 = c[i][jp * 2 + 0];
            float v1 = c[i][jp * 2 + 1];
            size_t base = ((size_t)(b_ * NH + h) * Tt + t_) * HD + d;
            if (sect == 2) {
                Vo[base]     = v0;
                Vo[base + 1] = v1;
            } else {
                float freq = expf(-(float)d * (LOG_THETA / 64.0f));
                float ang  = (float)t_ * freq;
                float sn = sinf(ang);
                float cs = cosf(ang);
                float e0 = v0 * cs - v1 * sn;
                float e1 = v0 * sn + v1 * cs;
                float* dst = (sect == 0) ? Qo : Ko;
                dst[base]     = e0;
                dst[base + 1] = e1;
            }
        }
    }
}

// ---------------------------------------------------------------------------
// Kernel 2: causal flash attention, fp32.
// Grid: (T/64, B*NH). Block 256 = 64 q-rows x 4 threads.
// Thread (r = tid>>2, s = tid&3) handles q-row r, k-columns j = jj*4+s.
// K/V tiles staged in LDS with stride 68 floats (16B-aligned rows,
// 4 consecutive rows land on distinct bank quads for ds_read_b128).
// ---------------------------------------------------------------------------
__global__ __launch_bounds__(256) void attn_fwd(
    const float* __restrict__ Q, const float* __restrict__ K,
    const float* __restrict__ V, float* __restrict__ O)
{
    __shared__ float Ks[64][68];
    __shared__ float Vs[64][68];

    const int tid  = threadIdx.x;
    const int r    = tid >> 2;
    const int s    = tid & 3;
    const int bh   = blockIdx.y;
    const int qi   = blockIdx.x;
    const int qrow = qi * 64 + r;

    // Load this thread's q row (scaled by 1/sqrt(64)).
    const float* qp = Q + ((size_t)bh * Tt + qrow) * HD;
    float q_reg[64];
    #pragma unroll
    for (int d4 = 0; d4 < 16; ++d4) {
        float4 qv = reinterpret_cast<const float4*>(qp)[d4];
        q_reg[d4 * 4 + 0] = qv.x * 0.125f;
        q_reg[d4 * 4 + 1] = qv.y * 0.125f;
        q_reg[d4 * 4 + 2] = qv.z * 0.125f;
        q_reg[d4 * 4 + 3] = qv.w * 0.125f;
    }

    float m = -INFINITY, l = 0.0f;
    float oacc[64] = {};

    const int lrow = tid >> 2;          // 0..63
    const int lcol = (tid & 3) * 16;    // 0,16,32,48

    for (int ki = 0; ki <= qi; ++ki) {
        const float* kp = K + ((size_t)bh * Tt + ki * 64) * HD;
        const float* vp = V + ((size_t)bh * Tt + ki * 64) * HD;
        #pragma unroll
        for (int w = 0; w < 4; ++w) {
            float4 kv = *reinterpret_cast<const float4*>(kp + lrow * 64 + lcol + w * 4);
            float4 vv = *reinterpret_cast<const float4*>(vp + lrow * 64 + lcol + w * 4);
            *reinterpret_cast<float4*>(&Ks[lrow][lcol + w * 4]) = kv;
            *reinterpret_cast<float4*>(&Vs[lrow][lcol + w * 4]) = vv;
        }
        __syncthreads();

        // Scores for this thread's 16 k-columns.
        float p[16];
        float tmax = -INFINITY;
        #pragma unroll
        for (int jj = 0; jj < 16; ++jj) {
            int j    = jj * 4 + s;
            int kcol = ki * 64 + j;
            const float* kr = &Ks[j][0];
            float dot = 0.0f;
            #pragma unroll
            for (int d4 = 0; d4 < 16; ++d4) {
                float4 kv = *reinterpret_cast<const float4*>(kr + d4 * 4);
                dot += q_reg[d4 * 4 + 0] * kv.x + q_reg[d4 * 4 + 1] * kv.y
                     + q_reg[d4 * 4 + 2] * kv.z + q_reg[d4 * 4 + 3] * kv.w;
            }
            dot   = (kcol <= qrow) ? dot : -INFINITY;
            p[jj] = dot;
            tmax  = fmaxf(tmax, dot);
        }
        // Row max across the 4-lane group.
        tmax = fmaxf(tmax, __shfl_xor(tmax, 1));
        tmax = fmaxf(tmax, __shfl_xor(tmax, 2));
        float mnew  = fmaxf(m, tmax);
        float scale = expf(m - mnew);   // m=-inf on first tile -> 0

        float psum = 0.0f;
        #pragma unroll
        for (int jj = 0; jj < 16; ++jj) {
            p[jj] = expf(p[jj] - mnew);
            psum += p[jj];
        }
        psum += __shfl_xor(psum, 1);
        psum += __shfl_xor(psum, 2);
        l = l * scale + psum;
        m = mnew;

        #pragma unroll
        for (int d = 0; d < 64; ++d) oacc[d] *= scale;

        #pragma unroll
        for (int jj = 0; jj < 16; ++jj) {
            float pj = p[jj];
            int j    = jj * 4 + s;
            const float* vr = &Vs[j][0];
            #pragma unroll
            for (int d4 = 0; d4 < 16; ++d4) {
                float4 vv = *reinterpret_cast<const float4*>(vr + d4 * 4);
                oacc[d4 * 4 + 0] += pj * vv.x;
                oacc[d4 * 4 + 1] += pj * vv.y;
                oacc[d4 * 4 + 2] += pj * vv.z;
                oacc[d4 * 4 + 3] += pj * vv.w;
            }
        }
        __syncthreads();
    }

    // Combine the 4 partial o-rows.
    #pragma unroll
    for (int d = 0; d < 64; ++d) {
        oacc[d] += __shfl_xor(oacc[d], 1);
        oacc[d] += __shfl_xor(oacc[d], 2);
    }
    float inv_l = 1.0f / l;

    const int b_ = bh >> 4;
    const int h  = bh & 15;
    float* op = O + ((size_t)b_ * Tt + qrow) * DM + h * HD;
    #pragma unroll
    for (int w = 0; w < 4; ++w) {
        float4 ov;
        ov.x = oacc[s * 16 + w * 4 + 0] * inv_l;
        ov.y = oacc[s * 16 + w * 4 + 1] * inv_l;
        ov.z = oacc[s * 16 + w * 4 + 2] * inv_l;
        ov.w = oacc[s * 16 + w * 4 + 3] * inv_l;
        *reinterpret_cast<float4*>(op + s * 16 + w * 4) = ov;
    }
}

// ---------------------------------------------------------------------------
// Kernel 3: output GEMM (M=8192, N=1024, K=1024), Out = O * W_out^T.
// ---------------------------------------------------------------------------
__global__ __launch_bounds__(256) void gemm_out(
    const float* __restrict__ Xo, const float* __restrict__ W,
    float* __restrict__ Out)
{
    __shared__ float As[16][65];
    __shared__ float Bs[16][65];
    const int tid = threadIdx.x;
    const int bm  = blockIdx.y * 64;
    const int bn  = blockIdx.x * 64;
    const int tx  = tid & 15;
    const int ty  = tid >> 4;
    const int lm  = tid >> 2;
    const int lk  = (tid & 3) * 4;

    float c[4][4] = {};

    const float* xp = Xo + (size_t)(bm + lm) * 1024 + lk;
    const float* wp = W  + (size_t)(bn + lm) * 1024 + lk;

    for (int k0 = 0; k0 < 1024; k0 += 16) {
        float4 av = *reinterpret_cast<const float4*>(xp + k0);
        float4 bv = *reinterpret_cast<const float4*>(wp + k0);
        As[lk + 0][lm] = av.x; As[lk + 1][lm] = av.y;
        As[lk + 2][lm] = av.z; As[lk + 3][lm] = av.w;
        Bs[lk + 0][lm] = bv.x; Bs[lk + 1][lm] = bv.y;
        Bs[lk + 2][lm] = bv.z; Bs[lk + 3][lm] = bv.w;
        __syncthreads();
        #pragma unroll
        for (int k = 0; k < 16; ++k) {
            float a0 = As[k][ty * 4 + 0], a1 = As[k][ty * 4 + 1];
            float a2 = As[k][ty * 4 + 2], a3 = As[k][ty * 4 + 3];
            float b0 = Bs[k][tx * 4 + 0], b1 = Bs[k][tx * 4 + 1];
            float b2 = Bs[k][tx * 4 + 2], b3 = Bs[k][tx * 4 + 3];
            c[0][0] += a0 * b0; c[0][1] += a0 * b1; c[0][2] += a0 * b2; c[0][3] += a0 * b3;
            c[1][0] += a1 * b0; c[1][1] += a1 * b1; c[1][2] += a1 * b2; c[1][3] += a1 * b3;
            c[2][0] += a2 * b0; c[2][1] += a2 * b1; c[2][2] += a2 * b2; c[2][3] += a2 * b3;
            c[3][0] += a3 * b0; c[3][1] += a3 * b1; c[3][2] += a3 * b2; c[3][3] += a3 * b3;
        }
        __syncthreads();
    }

    #pragma unroll
    for (int i = 0; i < 4; ++i) {
        int row = bm + ty * 4 + i;
        float4 ov;
        ov.x = c[i][0]; ov.y = c[i][1]; ov.z = c[i][2]; ov.w = c[i][3];
        *reinterpret_cast<float4*>(Out + (size_t)row * 1024 + bn + tx * 4) = ov;
    }
}

// ---------------------------------------------------------------------------
extern "C" void kernel_launch(void* const* d_in, const int* in_sizes, int n_in,
                              void* d_out, int out_size, void* d_ws, size_t ws_size,
                              hipStream_t stream)
{
    const float* x    = (const float*)d_in[0];   // (4, 2048, 1024)
    const float* wqkv = (const float*)d_in[1];   // (3072, 1024)
    const float* wout = (const float*)d_in[2];   // (1024, 1024)
    float* out = (float*)d_out;                  // (4, 2048, 1024)

    float* ws = (float*)d_ws;
    const size_t SEG = (size_t)Bb * NH * Tt * HD;  // 8388608 floats = 32 MB
    float* Qw = ws;
    float* Kw = ws + SEG;
    float* Vw = ws + 2 * SEG;
    float* Ow = ws + 3 * SEG;

    dim3 g1(3072 / 64, MBT / 64);   // (48, 128)
    gemm_qkv_rope<<<g1, 256, 0, stream>>>(x, wqkv, Qw, Kw, Vw);

    dim3 g2(Tt / 64, Bb * NH);      // (32, 64)
    attn_fwd<<<g2, 256, 0, stream>>>(Qw, Kw, Vw, Ow);

    dim3 g3(1024 / 64, MBT / 64);   // (16, 128)
    gemm_out<<<g3, 256, 0, stream>>>(Ow, wout, out);
}

// Round 6
// 4108.443 us; speedup vs baseline: 4.2114x; 4.2114x over previous
//
#include <hip/hip_runtime.h>
#include <hip/hip_bf16.h>
#include <math.h>

// Problem constants
constexpr int Bb  = 4;
constexpr int Tt  = 2048;
constexpr int DM  = 1024;
constexpr int NH  = 16;
constexpr int HD  = 64;
constexpr int MBT = Bb * Tt;                       // 8192
constexpr float LOG_THETA = 9.210340371976184f;    // ln(10000)

using bf16x8 = __attribute__((ext_vector_type(8))) short;   // 8 bf16 (4 VGPRs)
using f32x4  = __attribute__((ext_vector_type(4))) float;   // MFMA accumulator

__device__ inline short f2bf(float x) {
    __hip_bfloat16 h = __float2bfloat16(x);
    return *reinterpret_cast<short*>(&h);
}
__device__ inline float bf2f(short u) {
    __hip_bfloat16 h;
    *reinterpret_cast<short*>(&h) = u;
    return __bfloat162float(h);
}
__device__ inline unsigned int packbf2(float x) {
    short h  = f2bf(x);
    short lo = f2bf(x - bf2f(h));
    return (unsigned int)(unsigned short)h | ((unsigned int)(unsigned short)lo << 16);
}

// ---------------------------------------------------------------------------
// RoPE cos/sin table: tab[t*64 + 2p] = cos(t*theta^(-2p/64)), +1 = sin.
// ---------------------------------------------------------------------------
__global__ __launch_bounds__(256) void rope_table(float* __restrict__ tab)
{
    int i = blockIdx.x * 256 + threadIdx.x;   // 0..65535
    int t = i >> 5, p = i & 31;
    float freq = expf(-(float)(2 * p) * (LOG_THETA / 64.0f));
    float ang  = (float)t * freq;
    tab[t * 64 + 2 * p]     = cosf(ang);
    tab[t * 64 + 2 * p + 1] = sinf(ang);
}

// ---------------------------------------------------------------------------
// fp32 -> bf16 hi/lo split (hi = rne(x), lo = rne(x - hi)). 4 elems/thread.
// ---------------------------------------------------------------------------
__global__ __launch_bounds__(256) void cast_split(
    const float* __restrict__ src, short* __restrict__ hi,
    short* __restrict__ lo, int n4)
{
    int i = blockIdx.x * 256 + threadIdx.x;
    if (i >= n4) return;
    float4 v = reinterpret_cast<const float4*>(src)[i];
    short h0 = f2bf(v.x), h1 = f2bf(v.y), h2 = f2bf(v.z), h3 = f2bf(v.w);
    short l0 = f2bf(v.x - bf2f(h0));
    short l1 = f2bf(v.y - bf2f(h1));
    short l2 = f2bf(v.z - bf2f(h2));
    short l3 = f2bf(v.w - bf2f(h3));
    reinterpret_cast<short4*>(hi)[i] = make_short4(h0, h1, h2, h3);
    reinterpret_cast<short4*>(lo)[i] = make_short4(l0, l1, l2, l3);
}

// ---------------------------------------------------------------------------
// Kernel 1: QKV GEMM via bf16x3 MFMA (~fp32 precision).
// C[8192,3072] = X * Wqkv^T. 128x128 tile, BK=32, 4 waves (2x2), 4x4 frags.
// Epilogue: RoPE (table) + scatter to Q/K/V fp32 [B][H][T][64].
// ---------------------------------------------------------------------------
__global__ __launch_bounds__(256) void gemm_qkv_mfma(
    const short* __restrict__ Xhi, const short* __restrict__ Xlo,
    const short* __restrict__ Whi, const short* __restrict__ Wlo,
    const float* __restrict__ tab,
    float* __restrict__ Qo, float* __restrict__ Ko, float* __restrict__ Vo)
{
    __shared__ __align__(16) short Ah[4096], Al[4096], Bh[4096], Bl[4096];
    const int tid = threadIdx.x;
    const int bm  = blockIdx.y * 128;
    const int bn  = blockIdx.x * 128;
    const int w   = tid >> 6, l = tid & 63;
    const int wr  = w >> 1,  wc = w & 1;

    // Staging: tile = 512 chunks of 8 bf16; thread owns chunks tid, tid+256.
    // chunk ch -> row ch>>2, col8 (ch&3)*8 ; LDS linear offset = ch*8.
    const int r0 = tid >> 2;
    const int c0 = (tid & 3) * 8;
    const size_t ga0 = (size_t)(bm + r0) * 1024 + c0;
    const size_t ga1 = (size_t)(bm + r0 + 64) * 1024 + c0;
    const size_t gb0 = (size_t)(bn + r0) * 1024 + c0;
    const size_t gb1 = (size_t)(bn + r0 + 64) * 1024 + c0;

    f32x4 acc[4][4];
    #pragma unroll
    for (int m = 0; m < 4; ++m)
        #pragma unroll
        for (int n = 0; n < 4; ++n) acc[m][n] = (f32x4){0.f, 0.f, 0.f, 0.f};

    // Prefetch k0 = 0.
    float4 pah0 = *(const float4*)(Xhi + ga0);
    float4 pah1 = *(const float4*)(Xhi + ga1);
    float4 pal0 = *(const float4*)(Xlo + ga0);
    float4 pal1 = *(const float4*)(Xlo + ga1);
    float4 pbh0 = *(const float4*)(Whi + gb0);
    float4 pbh1 = *(const float4*)(Whi + gb1);
    float4 pbl0 = *(const float4*)(Wlo + gb0);
    float4 pbl1 = *(const float4*)(Wlo + gb1);

    for (int k0 = 0; k0 < 1024; k0 += 32) {
        __syncthreads();   // previous compute done, LDS free
        *(float4*)&Ah[tid * 8] = pah0;  *(float4*)&Ah[(tid + 256) * 8] = pah1;
        *(float4*)&Al[tid * 8] = pal0;  *(float4*)&Al[(tid + 256) * 8] = pal1;
        *(float4*)&Bh[tid * 8] = pbh0;  *(float4*)&Bh[(tid + 256) * 8] = pbh1;
        *(float4*)&Bl[tid * 8] = pbl0;  *(float4*)&Bl[(tid + 256) * 8] = pbl1;
        int kn = (k0 + 32) & 1023;     // wraps harmlessly on last iter
        pah0 = *(const float4*)(Xhi + ga0 + kn);
        pah1 = *(const float4*)(Xhi + ga1 + kn);
        pal0 = *(const float4*)(Xlo + ga0 + kn);
        pal1 = *(const float4*)(Xlo + ga1 + kn);
        pbh0 = *(const float4*)(Whi + gb0 + kn);
        pbh1 = *(const float4*)(Whi + gb1 + kn);
        pbl0 = *(const float4*)(Wlo + gb0 + kn);
        pbl1 = *(const float4*)(Wlo + gb1 + kn);
        __syncthreads();

        const int fr = l & 15;
        const int fg = (l >> 4) * 8;
        bf16x8 ah[4], alo[4], bh[4], blo[4];
        #pragma unroll
        for (int m = 0; m < 4; ++m) {
            int ro = (wr * 64 + m * 16 + fr) * 32 + fg;
            ah[m]  = *(const bf16x8*)&Ah[ro];
            alo[m] = *(const bf16x8*)&Al[ro];
        }
        #pragma unroll
        for (int n = 0; n < 4; ++n) {
            int ro = (wc * 64 + n * 16 + fr) * 32 + fg;
            bh[n]  = *(const bf16x8*)&Bh[ro];
            blo[n] = *(const bf16x8*)&Bl[ro];
        }
        #pragma unroll
        for (int m = 0; m < 4; ++m)
            #pragma unroll
            for (int n = 0; n < 4; ++n) {
                acc[m][n] = __builtin_amdgcn_mfma_f32_16x16x32_bf16(ah[m],  bh[n],  acc[m][n], 0, 0, 0);
                acc[m][n] = __builtin_amdgcn_mfma_f32_16x16x32_bf16(ah[m],  blo[n], acc[m][n], 0, 0, 0);
                acc[m][n] = __builtin_amdgcn_mfma_f32_16x16x32_bf16(alo[m], bh[n],  acc[m][n], 0, 0, 0);
            }
    }

    // Epilogue: C/D layout col = lane&15, row = (lane>>4)*4 + reg (m89).
    // RoPE pairs (even,odd cols) live in adjacent lanes -> shfl_xor(1).
    const int fr = l & 15, fq = l >> 4;
    #pragma unroll
    for (int m = 0; m < 4; ++m) {
        #pragma unroll
        for (int n = 0; n < 4; ++n) {
            int col  = bn + wc * 64 + n * 16 + fr;
            int sect = col >> 10;          // 0=q 1=k 2=v (wave-uniform)
            int cc   = col & 1023;
            int hh   = cc >> 6, d = cc & 63;
            int de   = d & 62;
            float* dst = (sect == 0) ? Qo : ((sect == 1) ? Ko : Vo);
            #pragma unroll
            for (int i = 0; i < 4; ++i) {
                int r  = bm + wr * 64 + m * 16 + fq * 4 + i;
                int b_ = r >> 11, t_ = r & 2047;
                float v  = acc[m][n][i];
                float vn = __shfl_xor(v, 1);
                float outv;
                if (sect == 2) {
                    outv = v;
                } else {
                    float2 cssn = *(const float2*)(tab + t_ * 64 + de);
                    outv = (d & 1) ? (vn * cssn.y + v * cssn.x)
                                   : (v * cssn.x - vn * cssn.y);
                }
                size_t off = ((size_t)(b_ * NH + hh) * Tt + t_) * HD + d;
                dst[off] = outv;
            }
        }
    }
}

// ---------------------------------------------------------------------------
// Kernel 2: causal flash attention, fp32, all register arrays static-indexed.
// Output packed as bf16 hi|lo uint32 into the Q buffer (same element index as
// the Q cell this block alone reads -> race-free reuse).
// ---------------------------------------------------------------------------
__global__ __launch_bounds__(256) void attn_fwd(
    const float* Q, const float* __restrict__ K,
    const float* __restrict__ V, unsigned int* Opk)
{
    __shared__ float Ks[64][68];
    __shared__ float Vs[64][68];

    const int tid  = threadIdx.x;
    const int r    = tid >> 2;
    const int s    = tid & 3;
    const int bh   = blockIdx.y;
    const int qi   = blockIdx.x;
    const int qrow = qi * 64 + r;

    const float* qp = Q + ((size_t)bh * Tt + qrow) * HD;
    float q_reg[64];
    #pragma unroll
    for (int d4 = 0; d4 < 16; ++d4) {
        float4 qv = reinterpret_cast<const float4*>(qp)[d4];
        q_reg[d4 * 4 + 0] = qv.x * 0.125f;
        q_reg[d4 * 4 + 1] = qv.y * 0.125f;
        q_reg[d4 * 4 + 2] = qv.z * 0.125f;
        q_reg[d4 * 4 + 3] = qv.w * 0.125f;
    }

    float m = -INFINITY, lsum = 0.0f;
    float oacc[64] = {};

    const int lrow = tid >> 2;
    const int lcol = (tid & 3) * 16;

    for (int ki = 0; ki <= qi; ++ki) {
        const float* kp = K + ((size_t)bh * Tt + ki * 64) * HD;
        const float* vp = V + ((size_t)bh * Tt + ki * 64) * HD;
        #pragma unroll
        for (int wq = 0; wq < 4; ++wq) {
            float4 kv = *reinterpret_cast<const float4*>(kp + lrow * 64 + lcol + wq * 4);
            float4 vv = *reinterpret_cast<const float4*>(vp + lrow * 64 + lcol + wq * 4);
            *reinterpret_cast<float4*>(&Ks[lrow][lcol + wq * 4]) = kv;
            *reinterpret_cast<float4*>(&Vs[lrow][lcol + wq * 4]) = vv;
        }
        __syncthreads();

        float p[16];
        float tmax = -INFINITY;
        #pragma unroll
        for (int jj = 0; jj < 16; ++jj) {
            int j    = jj * 4 + s;
            int kcol = ki * 64 + j;
            const float* kr = &Ks[j][0];
            float dot = 0.0f;
            #pragma unroll
            for (int d4 = 0; d4 < 16; ++d4) {
                float4 kv = *reinterpret_cast<const float4*>(kr + d4 * 4);
                dot += q_reg[d4 * 4 + 0] * kv.x + q_reg[d4 * 4 + 1] * kv.y
                     + q_reg[d4 * 4 + 2] * kv.z + q_reg[d4 * 4 + 3] * kv.w;
            }
            dot   = (kcol <= qrow) ? dot : -INFINITY;
            p[jj] = dot;
            tmax  = fmaxf(tmax, dot);
        }
        tmax = fmaxf(tmax, __shfl_xor(tmax, 1));
        tmax = fmaxf(tmax, __shfl_xor(tmax, 2));
        float mnew  = fmaxf(m, tmax);
        float scale = expf(m - mnew);

        float psum = 0.0f;
        #pragma unroll
        for (int jj = 0; jj < 16; ++jj) {
            p[jj] = expf(p[jj] - mnew);
            psum += p[jj];
        }
        psum += __shfl_xor(psum, 1);
        psum += __shfl_xor(psum, 2);
        lsum = lsum * scale + psum;
        m = mnew;

        #pragma unroll
        for (int d = 0; d < 64; ++d) oacc[d] *= scale;

        #pragma unroll
        for (int jj = 0; jj < 16; ++jj) {
            float pj = p[jj];
            int j    = jj * 4 + s;
            const float* vr = &Vs[j][0];
            #pragma unroll
            for (int d4 = 0; d4 < 16; ++d4) {
                float4 vv = *reinterpret_cast<const float4*>(vr + d4 * 4);
                oacc[d4 * 4 + 0] += pj * vv.x;
                oacc[d4 * 4 + 1] += pj * vv.y;
                oacc[d4 * 4 + 2] += pj * vv.z;
                oacc[d4 * 4 + 3] += pj * vv.w;
            }
        }
        __syncthreads();
    }

    #pragma unroll
    for (int d = 0; d < 64; ++d) {
        oacc[d] += __shfl_xor(oacc[d], 1);
        oacc[d] += __shfl_xor(oacc[d], 2);
    }
    float inv_l = 1.0f / lsum;

    if (s == 0) {
        unsigned int* op = Opk + ((size_t)bh * Tt + qrow) * HD;
        #pragma unroll
        for (int d4 = 0; d4 < 16; ++d4) {
            uint4 pv;
            pv.x = packbf2(oacc[d4 * 4 + 0] * inv_l);
            pv.y = packbf2(oacc[d4 * 4 + 1] * inv_l);
            pv.z = packbf2(oacc[d4 * 4 + 2] * inv_l);
            pv.w = packbf2(oacc[d4 * 4 + 3] * inv_l);
            *reinterpret_cast<uint4*>(op + d4 * 4) = pv;
        }
    }
}

// ---------------------------------------------------------------------------
// Kernel 3: Out[8192,1024] = O * Wout^T, bf16x3 MFMA. A operand unpacked from
// packed hi|lo uint32 in [B][H][T][64] order.
// ---------------------------------------------------------------------------
__global__ __launch_bounds__(256) void gemm_out_mfma(
    const unsigned int* __restrict__ Opk,
    const short* __restrict__ WOhi, const short* __restrict__ WOlo,
    float* __restrict__ Out)
{
    __shared__ __align__(16) short Ah[4096], Al[4096], Bh[4096], Bl[4096];
    const int tid = threadIdx.x;
    const int bm  = blockIdx.y * 128;
    const int bn  = blockIdx.x * 128;
    const int w   = tid >> 6, l = tid & 63;
    const int wr  = w >> 1,  wc = w & 1;

    const int r0 = tid >> 2;
    const int c8 = (tid & 3) * 8;
    const int rA0 = bm + r0, rA1 = bm + r0 + 64;
    const int b0 = rA0 >> 11, t0 = rA0 & 2047;
    const int b1 = rA1 >> 11, t1 = rA1 & 2047;
    const size_t gb0 = (size_t)(bn + r0) * 1024 + c8;
    const size_t gb1 = (size_t)(bn + r0 + 64) * 1024 + c8;

    f32x4 acc[4][4];
    #pragma unroll
    for (int m = 0; m < 4; ++m)
        #pragma unroll
        for (int n = 0; n < 4; ++n) acc[m][n] = (f32x4){0.f, 0.f, 0.f, 0.f};

    uint4 ua0, ua1, ua2, ua3;
    float4 pbh0, pbh1, pbl0, pbl1;
    {
        int c = c8;                       // k0 = 0
        int hh = c >> 6, d = c & 63;
        size_t ia0 = ((size_t)(b0 * NH + hh) * Tt + t0) * 64 + d;
        size_t ia1 = ((size_t)(b1 * NH + hh) * Tt + t1) * 64 + d;
        ua0 = *(const uint4*)(Opk + ia0);  ua1 = *(const uint4*)(Opk + ia0 + 4);
        ua2 = *(const uint4*)(Opk + ia1);  ua3 = *(const uint4*)(Opk + ia1 + 4);
        pbh0 = *(const float4*)(WOhi + gb0);
        pbh1 = *(const float4*)(WOhi + gb1);
        pbl0 = *(const float4*)(WOlo + gb0);
        pbl1 = *(const float4*)(WOlo + gb1);
    }

    for (int k0 = 0; k0 < 1024; k0 += 32) {
        __syncthreads();
        {
            bf16x8 H, L;
            H[0] = (short)ua0.x; L[0] = (short)(ua0.x >> 16);
            H[1] = (short)ua0.y; L[1] = (short)(ua0.y >> 16);
            H[2] = (short)ua0.z; L[2] = (short)(ua0.z >> 16);
            H[3] = (short)ua0.w; L[3] = (short)(ua0.w >> 16);
            H[4] = (short)ua1.x; L[4] = (short)(ua1.x >> 16);
            H[5] = (short)ua1.y; L[5] = (short)(ua1.y >> 16);
            H[6] = (short)ua1.z; L[6] = (short)(ua1.z >> 16);
            H[7] = (short)ua1.w; L[7] = (short)(ua1.w >> 16);
            *(bf16x8*)&Ah[tid * 8] = H;  *(bf16x8*)&Al[tid * 8] = L;
            H[0] = (short)ua2.x; L[0] = (short)(ua2.x >> 16);
            H[1] = (short)ua2.y; L[1] = (short)(ua2.y >> 16);
            H[2] = (short)ua2.z; L[2] = (short)(ua2.z >> 16);
            H[3] = (short)ua2.w; L[3] = (short)(ua2.w >> 16);
            H[4] = (short)ua3.x; L[4] = (short)(ua3.x >> 16);
            H[5] = (short)ua3.y; L[5] = (short)(ua3.y >> 16);
            H[6] = (short)ua3.z; L[6] = (short)(ua3.z >> 16);
            H[7] = (short)ua3.w; L[7] = (short)(ua3.w >> 16);
            *(bf16x8*)&Ah[(tid + 256) * 8] = H;  *(bf16x8*)&Al[(tid + 256) * 8] = L;
        }
        *(float4*)&Bh[tid * 8] = pbh0;  *(float4*)&Bh[(tid + 256) * 8] = pbh1;
        *(float4*)&Bl[tid * 8] = pbl0;  *(float4*)&Bl[(tid + 256) * 8] = pbl1;

        int kn = (k0 + 32) & 1023;
        {
            int c = kn + c8;
            int hh = c >> 6, d = c & 63;
            size_t ia0 = ((size_t)(b0 * NH + hh) * Tt + t0) * 64 + d;
            size_t ia1 = ((size_t)(b1 * NH + hh) * Tt + t1) * 64 + d;
            ua0 = *(const uint4*)(Opk + ia0);  ua1 = *(const uint4*)(Opk + ia0 + 4);
            ua2 = *(const uint4*)(Opk + ia1);  ua3 = *(const uint4*)(Opk + ia1 + 4);
            pbh0 = *(const float4*)(WOhi + gb0 + kn);
            pbh1 = *(const float4*)(WOhi + gb1 + kn);
            pbl0 = *(const float4*)(WOlo + gb0 + kn);
            pbl1 = *(const float4*)(WOlo + gb1 + kn);
        }
        __syncthreads();

        const int fr = l & 15;
        const int fg = (l >> 4) * 8;
        bf16x8 ah[4], alo[4], bh[4], blo[4];
        #pragma unroll
        for (int m = 0; m < 4; ++m) {
            int ro = (wr * 64 + m * 16 + fr) * 32 + fg;
            ah[m]  = *(const bf16x8*)&Ah[ro];
            alo[m] = *(const bf16x8*)&Al[ro];
        }
        #pragma unroll
        for (int n = 0; n < 4; ++n) {
            int ro = (wc * 64 + n * 16 + fr) * 32 + fg;
            bh[n]  = *(const bf16x8*)&Bh[ro];
            blo[n] = *(const bf16x8*)&Bl[ro];
        }
        #pragma unroll
        for (int m = 0; m < 4; ++m)
            #pragma unroll
            for (int n = 0; n < 4; ++n) {
                acc[m][n] = __builtin_amdgcn_mfma_f32_16x16x32_bf16(ah[m],  bh[n],  acc[m][n], 0, 0, 0);
                acc[m][n] = __builtin_amdgcn_mfma_f32_16x16x32_bf16(ah[m],  blo[n], acc[m][n], 0, 0, 0);
                acc[m][n] = __builtin_amdgcn_mfma_f32_16x16x32_bf16(alo[m], bh[n],  acc[m][n], 0, 0, 0);
            }
    }

    const int fr = l & 15, fq = l >> 4;
    #pragma unroll
    for (int m = 0; m < 4; ++m)
        #pragma unroll
        for (int n = 0; n < 4; ++n) {
            int col = bn + wc * 64 + n * 16 + fr;
            #pragma unroll
            for (int i = 0; i < 4; ++i) {
                int r = bm + wr * 64 + m * 16 + fq * 4 + i;
                Out[(size_t)r * 1024 + col] = acc[m][n][i];
            }
        }
}

// ---------------------------------------------------------------------------
extern "C" void kernel_launch(void* const* d_in, const int* in_sizes, int n_in,
                              void* d_out, int out_size, void* d_ws, size_t ws_size,
                              hipStream_t stream)
{
    const float* x    = (const float*)d_in[0];   // (4, 2048, 1024)
    const float* wqkv = (const float*)d_in[1];   // (3072, 1024)
    const float* wout = (const float*)d_in[2];   // (1024, 1024)
    float* out = (float*)d_out;

    // ws layout (<=113 MB):
    //   [0,32M):   Q fp32  -> later packed O (bf16 hi|lo per uint32, same idx)
    //   [32,64M):  K fp32
    //   [64,96M):  V fp32
    //   [96,102M): Wqkv hi   [102,108M): Wqkv lo
    //   [108,110M): Wout hi  [110,112M): Wout lo
    //   [112M,+512K): rope table
    // d_out (32 MB) holds Xhi/Xlo until gemm_out overwrites it.
    char* wsb = (char*)d_ws;
    float*        Qf  = (float*)(wsb);
    unsigned int* Opk = (unsigned int*)(wsb);
    float*        Kf  = (float*)(wsb + (size_t)32  * 1048576);
    float*        Vf  = (float*)(wsb + (size_t)64  * 1048576);
    short*        Whi = (short*)(wsb + (size_t)96  * 1048576);
    short*        Wlo = (short*)(wsb + (size_t)102 * 1048576);
    short*        WOhi= (short*)(wsb + (size_t)108 * 1048576);
    short*        WOlo= (short*)(wsb + (size_t)110 * 1048576);
    float*        tab = (float*)(wsb + (size_t)112 * 1048576);

    short* Xhi = (short*)d_out;
    short* Xlo = (short*)d_out + 8388608;

    rope_table<<<256, 256, 0, stream>>>(tab);
    cast_split<<<8192, 256, 0, stream>>>(x,    Xhi,  Xlo,  2097152);
    cast_split<<<3072, 256, 0, stream>>>(wqkv, Whi,  Wlo,  786432);
    cast_split<<<1024, 256, 0, stream>>>(wout, WOhi, WOlo, 262144);

    dim3 g1(24, 64);
    gemm_qkv_mfma<<<g1, 256, 0, stream>>>(Xhi, Xlo, Whi, Wlo, tab, Qf, Kf, Vf);

    dim3 g2(32, 64);
    attn_fwd<<<g2, 256, 0, stream>>>(Qf, Kf, Vf, Opk);

    dim3 g3(8, 64);
    gemm_out_mfma<<<g3, 256, 0, stream>>>(Opk, WOhi, WOlo, out);
}

// Round 7
// 745.255 us; speedup vs baseline: 23.2163x; 5.5128x over previous
//
#include <hip/hip_runtime.h>
#include <hip/hip_bf16.h>
#include <math.h>

// Problem constants
constexpr int Bb  = 4;
constexpr int Tt  = 2048;
constexpr int DM  = 1024;
constexpr int NH  = 16;
constexpr int HD  = 64;
constexpr int MBT = Bb * Tt;                       // 8192
constexpr float LOG_THETA = 9.210340371976184f;    // ln(10000)

using bf16x8 = __attribute__((ext_vector_type(8))) short;   // 8 bf16 (4 VGPRs)
using f32x4  = __attribute__((ext_vector_type(4))) float;   // MFMA accumulator

__device__ inline short f2bf(float x) {
    __hip_bfloat16 h = __float2bfloat16(x);
    return *reinterpret_cast<short*>(&h);
}
__device__ inline float bf2f(short u) {
    __hip_bfloat16 h;
    *reinterpret_cast<short*>(&h) = u;
    return __bfloat162float(h);
}
__device__ inline unsigned int packbf2(float x) {
    short h  = f2bf(x);
    short lo = f2bf(x - bf2f(h));
    return (unsigned int)(unsigned short)h | ((unsigned int)(unsigned short)lo << 16);
}
// 8 fp32 -> bf16 hi/lo vectors (all indices static after unroll)
__device__ inline void split8(float4 a, float4 b, bf16x8& H, bf16x8& L) {
    float x[8] = {a.x, a.y, a.z, a.w, b.x, b.y, b.z, b.w};
    #pragma unroll
    for (int e = 0; e < 8; ++e) {
        short h = f2bf(x[e]);
        H[e] = h;
        L[e] = f2bf(x[e] - bf2f(h));
    }
}

// ---------------------------------------------------------------------------
// RoPE cos/sin table: tab[t*64 + 2p] = cos(t*theta^(-2p/64)), +1 = sin.
// ---------------------------------------------------------------------------
__global__ __launch_bounds__(256) void rope_table(float* __restrict__ tab)
{
    int i = blockIdx.x * 256 + threadIdx.x;   // 0..65535
    int t = i >> 5, p = i & 31;
    float freq = expf(-(float)(2 * p) * (LOG_THETA / 64.0f));
    float ang  = (float)t * freq;
    tab[t * 64 + 2 * p]     = cosf(ang);
    tab[t * 64 + 2 * p + 1] = sinf(ang);
}

// ---------------------------------------------------------------------------
// fp32 -> bf16 hi/lo split arrays. 4 elems/thread.
// ---------------------------------------------------------------------------
__global__ __launch_bounds__(256) void cast_split(
    const float* __restrict__ src, short* __restrict__ hi,
    short* __restrict__ lo, int n4)
{
    int i = blockIdx.x * 256 + threadIdx.x;
    if (i >= n4) return;
    float4 v = reinterpret_cast<const float4*>(src)[i];
    short h0 = f2bf(v.x), h1 = f2bf(v.y), h2 = f2bf(v.z), h3 = f2bf(v.w);
    short l0 = f2bf(v.x - bf2f(h0));
    short l1 = f2bf(v.y - bf2f(h1));
    short l2 = f2bf(v.z - bf2f(h2));
    short l3 = f2bf(v.w - bf2f(h3));
    reinterpret_cast<short4*>(hi)[i] = make_short4(h0, h1, h2, h3);
    reinterpret_cast<short4*>(lo)[i] = make_short4(l0, l1, l2, l3);
}

// ---------------------------------------------------------------------------
// Kernel 1: QKV GEMM via bf16x3 MFMA (~fp32 precision).
// C[8192,3072] = X * Wqkv^T. 128x128 tile, BK=32, 4 waves (2x2), 4x4 frags.
// Epilogue: RoPE + scatter. Q,K fp32 [B][H][T][64]; V stored TRANSPOSED as
// Vt fp32 [B][H][64 d][T] (feeds MFMA attention's B-operand directly).
// ---------------------------------------------------------------------------
__global__ __launch_bounds__(256) void gemm_qkv_mfma(
    const short* __restrict__ Xhi, const short* __restrict__ Xlo,
    const short* __restrict__ Whi, const short* __restrict__ Wlo,
    const float* __restrict__ tab,
    float* __restrict__ Qo, float* __restrict__ Ko, float* __restrict__ Vo)
{
    __shared__ __align__(16) short Ah[4096], Al[4096], Bh[4096], Bl[4096];
    const int tid = threadIdx.x;
    const int bm  = blockIdx.y * 128;
    const int bn  = blockIdx.x * 128;
    const int w   = tid >> 6, l = tid & 63;
    const int wr  = w >> 1,  wc = w & 1;

    const int r0 = tid >> 2;
    const int c0 = (tid & 3) * 8;
    const size_t ga0 = (size_t)(bm + r0) * 1024 + c0;
    const size_t ga1 = (size_t)(bm + r0 + 64) * 1024 + c0;
    const size_t gb0 = (size_t)(bn + r0) * 1024 + c0;
    const size_t gb1 = (size_t)(bn + r0 + 64) * 1024 + c0;

    f32x4 acc[4][4];
    #pragma unroll
    for (int m = 0; m < 4; ++m)
        #pragma unroll
        for (int n = 0; n < 4; ++n) acc[m][n] = (f32x4){0.f, 0.f, 0.f, 0.f};

    float4 pah0 = *(const float4*)(Xhi + ga0);
    float4 pah1 = *(const float4*)(Xhi + ga1);
    float4 pal0 = *(const float4*)(Xlo + ga0);
    float4 pal1 = *(const float4*)(Xlo + ga1);
    float4 pbh0 = *(const float4*)(Whi + gb0);
    float4 pbh1 = *(const float4*)(Whi + gb1);
    float4 pbl0 = *(const float4*)(Wlo + gb0);
    float4 pbl1 = *(const float4*)(Wlo + gb1);

    for (int k0 = 0; k0 < 1024; k0 += 32) {
        __syncthreads();
        *(float4*)&Ah[tid * 8] = pah0;  *(float4*)&Ah[(tid + 256) * 8] = pah1;
        *(float4*)&Al[tid * 8] = pal0;  *(float4*)&Al[(tid + 256) * 8] = pal1;
        *(float4*)&Bh[tid * 8] = pbh0;  *(float4*)&Bh[(tid + 256) * 8] = pbh1;
        *(float4*)&Bl[tid * 8] = pbl0;  *(float4*)&Bl[(tid + 256) * 8] = pbl1;
        int kn = (k0 + 32) & 1023;
        pah0 = *(const float4*)(Xhi + ga0 + kn);
        pah1 = *(const float4*)(Xhi + ga1 + kn);
        pal0 = *(const float4*)(Xlo + ga0 + kn);
        pal1 = *(const float4*)(Xlo + ga1 + kn);
        pbh0 = *(const float4*)(Whi + gb0 + kn);
        pbh1 = *(const float4*)(Whi + gb1 + kn);
        pbl0 = *(const float4*)(Wlo + gb0 + kn);
        pbl1 = *(const float4*)(Wlo + gb1 + kn);
        __syncthreads();

        const int fr = l & 15;
        const int fg = (l >> 4) * 8;
        bf16x8 ah[4], alo[4], bhv[4], blo[4];
        #pragma unroll
        for (int m = 0; m < 4; ++m) {
            int ro = (wr * 64 + m * 16 + fr) * 32 + fg;
            ah[m]  = *(const bf16x8*)&Ah[ro];
            alo[m] = *(const bf16x8*)&Al[ro];
        }
        #pragma unroll
        for (int n = 0; n < 4; ++n) {
            int ro = (wc * 64 + n * 16 + fr) * 32 + fg;
            bhv[n] = *(const bf16x8*)&Bh[ro];
            blo[n] = *(const bf16x8*)&Bl[ro];
        }
        #pragma unroll
        for (int m = 0; m < 4; ++m)
            #pragma unroll
            for (int n = 0; n < 4; ++n) {
                acc[m][n] = __builtin_amdgcn_mfma_f32_16x16x32_bf16(ah[m],  bhv[n], acc[m][n], 0, 0, 0);
                acc[m][n] = __builtin_amdgcn_mfma_f32_16x16x32_bf16(ah[m],  blo[n], acc[m][n], 0, 0, 0);
                acc[m][n] = __builtin_amdgcn_mfma_f32_16x16x32_bf16(alo[m], bhv[n], acc[m][n], 0, 0, 0);
            }
    }

    // Epilogue: C/D layout col = lane&15, row = (lane>>4)*4 + reg (m89).
    const int fr = l & 15, fq = l >> 4;
    #pragma unroll
    for (int m = 0; m < 4; ++m) {
        #pragma unroll
        for (int n = 0; n < 4; ++n) {
            int col  = bn + wc * 64 + n * 16 + fr;
            int sect = col >> 10;          // 0=q 1=k 2=v (wave-uniform)
            int cc   = col & 1023;
            int hh   = cc >> 6, d = cc & 63;
            int de   = d & 62;
            #pragma unroll
            for (int i = 0; i < 4; ++i) {
                int r  = bm + wr * 64 + m * 16 + fq * 4 + i;
                int b_ = r >> 11, t_ = r & 2047;
                float v  = acc[m][n][i];
                float vn = __shfl_xor(v, 1);
                if (sect == 2) {
                    // V transposed: Vt[bh][d][t]
                    Vo[((size_t)(b_ * NH + hh) * HD + d) * Tt + t_] = v;
                } else {
                    float2 cssn = *(const float2*)(tab + t_ * 64 + de);
                    float outv = (d & 1) ? (vn * cssn.y + v * cssn.x)
                                         : (v * cssn.x - vn * cssn.y);
                    float* dst = (sect == 0) ? Qo : Ko;
                    dst[((size_t)(b_ * NH + hh) * Tt + t_) * HD + d] = outv;
                }
            }
        }
    }
}

// ---------------------------------------------------------------------------
// Kernel 2: causal flash attention, MFMA bf16-hi/lo x3 (~fp32 precision).
// Grid (T/64, B*H). Block 256 = 4 waves; wave w owns q-rows [qi*64+w*16, +16).
// K tile [64 t][64 d] and Vt tile [64 d][64 t] staged as bf16 hi/lo in LDS
// with XOR swizzle byte^=(row&7)<<4 (conflict-uniform frag reads).
// Softmax: 16-lane-group shfl reduce; P routed via per-wave padded LDS
// ([16][68] u32 hi|lo) to convert C-layout -> A-fragment layout.
// Output packed bf16 hi|lo u32 into the Q buffer (block-exclusive rows).
// ---------------------------------------------------------------------------
__global__ __launch_bounds__(256) void attn_fwd_mfma(
    const float* Q, const float* __restrict__ K,
    const float* __restrict__ Vt, unsigned int* Opk)
{
    __shared__ __align__(16) short Khi[4096], Klo[4096], Vthi[4096], Vtlo[4096];
    __shared__ __align__(16) unsigned int Ppk[4][16][68];   // pad 64->68 (rows stay 16B-aligned)

    const int tid = threadIdx.x;
    const int w   = tid >> 6;
    const int l   = tid & 63;
    const int fr  = l & 15;
    const int hi8 = l >> 4;
    const int bh  = blockIdx.y;
    const int qi  = blockIdx.x;
    const int qbase = qi * 64 + w * 16;

    // ---- Q fragments (scale 1/8 folded in), bf16 hi/lo, 2 k-slabs ----
    bf16x8 qh[2], ql[2];
    {
        const float* qp = Q + ((size_t)bh * Tt + qbase + fr) * HD;
        #pragma unroll
        for (int s = 0; s < 2; ++s) {
            float4 a = *(const float4*)(qp + s * 32 + hi8 * 8);
            float4 b = *(const float4*)(qp + s * 32 + hi8 * 8 + 4);
            a.x *= 0.125f; a.y *= 0.125f; a.z *= 0.125f; a.w *= 0.125f;
            b.x *= 0.125f; b.y *= 0.125f; b.z *= 0.125f; b.w *= 0.125f;
            split8(a, b, qh[s], ql[s]);
        }
    }

    f32x4 acc_o[4];
    #pragma unroll
    for (int n = 0; n < 4; ++n) acc_o[n] = (f32x4){0.f, 0.f, 0.f, 0.f};
    float mreg[4] = {-INFINITY, -INFINITY, -INFINITY, -INFINITY};
    float lreg[4] = {0.f, 0.f, 0.f, 0.f};

    // staging mapping: thread -> (row sr, 16-col chunk sc)
    const int sr = tid >> 2;
    const int sc = (tid & 3) * 16;
    const float* kg = K  + ((size_t)bh * Tt + sr) * HD + sc;   // +ki*64*HD
    const float* vg = Vt + ((size_t)bh * HD + sr) * Tt + sc;   // +ki*64

    for (int ki = 0; ki <= qi; ++ki) {
        __syncthreads();   // previous tile's LDS reads complete
        {
            const float* kp = kg + (size_t)ki * 64 * HD;
            const float* vp = vg + ki * 64;
            #pragma unroll
            for (int h = 0; h < 2; ++h) {
                int off = (sc * 2 + h * 16) ^ ((sr & 7) << 4);
                float4 a = *(const float4*)(kp + h * 8);
                float4 b = *(const float4*)(kp + h * 8 + 4);
                bf16x8 H, L;
                split8(a, b, H, L);
                *(bf16x8*)((char*)Khi + sr * 128 + off) = H;
                *(bf16x8*)((char*)Klo + sr * 128 + off) = L;
                float4 c = *(const float4*)(vp + h * 8);
                float4 d = *(const float4*)(vp + h * 8 + 4);
                split8(c, d, H, L);
                *(bf16x8*)((char*)Vthi + sr * 128 + off) = H;
                *(bf16x8*)((char*)Vtlo + sr * 128 + off) = L;
            }
        }
        __syncthreads();

        // ---- S = Q·K^T (bf16x3): lane holds S[q=hi8*4+i][kcol=n*16+fr] ----
        f32x4 acc_s[4];
        #pragma unroll
        for (int n = 0; n < 4; ++n) acc_s[n] = (f32x4){0.f, 0.f, 0.f, 0.f};
        #pragma unroll
        for (int n = 0; n < 4; ++n) {
            int row = n * 16 + fr;
            const char* kh_ = (const char*)Khi + row * 128;
            const char* kl_ = (const char*)Klo + row * 128;
            #pragma unroll
            for (int s = 0; s < 2; ++s) {
                int off = (s * 64 + hi8 * 16) ^ ((row & 7) << 4);
                bf16x8 kh = *(const bf16x8*)(kh_ + off);
                bf16x8 kl = *(const bf16x8*)(kl_ + off);
                acc_s[n] = __builtin_amdgcn_mfma_f32_16x16x32_bf16(qh[s], kh, acc_s[n], 0, 0, 0);
                acc_s[n] = __builtin_amdgcn_mfma_f32_16x16x32_bf16(qh[s], kl, acc_s[n], 0, 0, 0);
                acc_s[n] = __builtin_amdgcn_mfma_f32_16x16x32_bf16(ql[s], kh, acc_s[n], 0, 0, 0);
            }
        }

        // ---- causal mask (diagonal tile only; branch wave-uniform) ----
        if (ki == qi) {
            #pragma unroll
            for (int n = 0; n < 4; ++n)
                #pragma unroll
                for (int i = 0; i < 4; ++i) {
                    int kc = ki * 64 + n * 16 + fr;
                    int qr = qbase + hi8 * 4 + i;
                    if (kc > qr) acc_s[n][i] = -INFINITY;
                }
        }

        // ---- online softmax (row reduce across the 16 fr-lanes) ----
        float tmax[4], scl[4], ps[4][4];
        #pragma unroll
        for (int i = 0; i < 4; ++i)
            tmax[i] = fmaxf(fmaxf(acc_s[0][i], acc_s[1][i]),
                            fmaxf(acc_s[2][i], acc_s[3][i]));
        #pragma unroll
        for (int i = 0; i < 4; ++i) {
            tmax[i] = fmaxf(tmax[i], __shfl_xor(tmax[i], 1));
            tmax[i] = fmaxf(tmax[i], __shfl_xor(tmax[i], 2));
            tmax[i] = fmaxf(tmax[i], __shfl_xor(tmax[i], 4));
            tmax[i] = fmaxf(tmax[i], __shfl_xor(tmax[i], 8));
        }
        #pragma unroll
        for (int i = 0; i < 4; ++i) {
            float mn = fmaxf(mreg[i], tmax[i]);
            scl[i]  = expf(mreg[i] - mn);
            mreg[i] = mn;
        }
        #pragma unroll
        for (int n = 0; n < 4; ++n)
            #pragma unroll
            for (int i = 0; i < 4; ++i)
                ps[n][i] = expf(acc_s[n][i] - mreg[i]);
        #pragma unroll
        for (int i = 0; i < 4; ++i) {
            float r = ps[0][i] + ps[1][i] + ps[2][i] + ps[3][i];
            r += __shfl_xor(r, 1);
            r += __shfl_xor(r, 2);
            r += __shfl_xor(r, 4);
            r += __shfl_xor(r, 8);
            lreg[i] = lreg[i] * scl[i] + r;
        }
        #pragma unroll
        for (int n = 0; n < 4; ++n)
            #pragma unroll
            for (int i = 0; i < 4; ++i)
                acc_o[n][i] *= scl[i];

        // ---- P: C-layout -> A-frag layout via per-wave LDS ----
        #pragma unroll
        for (int n = 0; n < 4; ++n)
            #pragma unroll
            for (int i = 0; i < 4; ++i)
                Ppk[w][hi8 * 4 + i][n * 16 + fr] = packbf2(ps[n][i]);

        bf16x8 pah[2], pal[2];
        #pragma unroll
        for (int s = 0; s < 2; ++s) {
            const unsigned int* pr = &Ppk[w][fr][s * 32 + hi8 * 8];
            uint4 u0 = *(const uint4*)pr;
            uint4 u1 = *(const uint4*)(pr + 4);
            unsigned int uu[8] = {u0.x, u0.y, u0.z, u0.w, u1.x, u1.y, u1.z, u1.w};
            #pragma unroll
            for (int e = 0; e < 8; ++e) {
                pah[s][e] = (short)(uu[e] & 0xffffu);
                pal[s][e] = (short)(uu[e] >> 16);
            }
        }

        // ---- O += P·V (bf16x3), Vt rows = d, k-contiguous ----
        #pragma unroll
        for (int n = 0; n < 4; ++n) {
            int row = n * 16 + fr;
            const char* vh_ = (const char*)Vthi + row * 128;
            const char* vl_ = (const char*)Vtlo + row * 128;
            #pragma unroll
            for (int s = 0; s < 2; ++s) {
                int off = (s * 64 + hi8 * 16) ^ ((row & 7) << 4);
                bf16x8 vh = *(const bf16x8*)(vh_ + off);
                bf16x8 vl = *(const bf16x8*)(vl_ + off);
                acc_o[n] = __builtin_amdgcn_mfma_f32_16x16x32_bf16(pah[s], vh, acc_o[n], 0, 0, 0);
                acc_o[n] = __builtin_amdgcn_mfma_f32_16x16x32_bf16(pah[s], vl, acc_o[n], 0, 0, 0);
                acc_o[n] = __builtin_amdgcn_mfma_f32_16x16x32_bf16(pal[s], vh, acc_o[n], 0, 0, 0);
            }
        }
    }

    // ---- epilogue: O/l, pack bf16 hi|lo, write into Q buffer slot ----
    float invl[4];
    #pragma unroll
    for (int i = 0; i < 4; ++i) invl[i] = 1.0f / lreg[i];
    unsigned int* op = Opk + ((size_t)bh * Tt + qbase) * HD;
    #pragma unroll
    for (int n = 0; n < 4; ++n)
        #pragma unroll
        for (int i = 0; i < 4; ++i)
            op[(size_t)(hi8 * 4 + i) * HD + n * 16 + fr] =
                packbf2(acc_o[n][i] * invl[i]);
}

// ---------------------------------------------------------------------------
// Kernel 3: Out[8192,1024] = O * Wout^T, bf16x3 MFMA. A operand unpacked from
// packed hi|lo uint32 in [B][H][T][64] order.
// ---------------------------------------------------------------------------
__global__ __launch_bounds__(256) void gemm_out_mfma(
    const unsigned int* __restrict__ Opk,
    const short* __restrict__ WOhi, const short* __restrict__ WOlo,
    float* __restrict__ Out)
{
    __shared__ __align__(16) short Ah[4096], Al[4096], Bh[4096], Bl[4096];
    const int tid = threadIdx.x;
    const int bm  = blockIdx.y * 128;
    const int bn  = blockIdx.x * 128;
    const int w   = tid >> 6, l = tid & 63;
    const int wr  = w >> 1,  wc = w & 1;

    const int r0 = tid >> 2;
    const int c8 = (tid & 3) * 8;
    const int rA0 = bm + r0, rA1 = bm + r0 + 64;
    const int b0 = rA0 >> 11, t0 = rA0 & 2047;
    const int b1 = rA1 >> 11, t1 = rA1 & 2047;
    const size_t gb0 = (size_t)(bn + r0) * 1024 + c8;
    const size_t gb1 = (size_t)(bn + r0 + 64) * 1024 + c8;

    f32x4 acc[4][4];
    #pragma unroll
    for (int m = 0; m < 4; ++m)
        #pragma unroll
        for (int n = 0; n < 4; ++n) acc[m][n] = (f32x4){0.f, 0.f, 0.f, 0.f};

    uint4 ua0, ua1, ua2, ua3;
    float4 pbh0, pbh1, pbl0, pbl1;
    {
        int c = c8;
        int hh = c >> 6, d = c & 63;
        size_t ia0 = ((size_t)(b0 * NH + hh) * Tt + t0) * 64 + d;
        size_t ia1 = ((size_t)(b1 * NH + hh) * Tt + t1) * 64 + d;
        ua0 = *(const uint4*)(Opk + ia0);  ua1 = *(const uint4*)(Opk + ia0 + 4);
        ua2 = *(const uint4*)(Opk + ia1);  ua3 = *(const uint4*)(Opk + ia1 + 4);
        pbh0 = *(const float4*)(WOhi + gb0);
        pbh1 = *(const float4*)(WOhi + gb1);
        pbl0 = *(const float4*)(WOlo + gb0);
        pbl1 = *(const float4*)(WOlo + gb1);
    }

    for (int k0 = 0; k0 < 1024; k0 += 32) {
        __syncthreads();
        {
            bf16x8 H, L;
            H[0] = (short)ua0.x; L[0] = (short)(ua0.x >> 16);
            H[1] = (short)ua0.y; L[1] = (short)(ua0.y >> 16);
            H[2] = (short)ua0.z; L[2] = (short)(ua0.z >> 16);
            H[3] = (short)ua0.w; L[3] = (short)(ua0.w >> 16);
            H[4] = (short)ua1.x; L[4] = (short)(ua1.x >> 16);
            H[5] = (short)ua1.y; L[5] = (short)(ua1.y >> 16);
            H[6] = (short)ua1.z; L[6] = (short)(ua1.z >> 16);
            H[7] = (short)ua1.w; L[7] = (short)(ua1.w >> 16);
            *(bf16x8*)&Ah[tid * 8] = H;  *(bf16x8*)&Al[tid * 8] = L;
            H[0] = (short)ua2.x; L[0] = (short)(ua2.x >> 16);
            H[1] = (short)ua2.y; L[1] = (short)(ua2.y >> 16);
            H[2] = (short)ua2.z; L[2] = (short)(ua2.z >> 16);
            H[3] = (short)ua2.w; L[3] = (short)(ua2.w >> 16);
            H[4] = (short)ua3.x; L[4] = (short)(ua3.x >> 16);
            H[5] = (short)ua3.y; L[5] = (short)(ua3.y >> 16);
            H[6] = (short)ua3.z; L[6] = (short)(ua3.z >> 16);
            H[7] = (short)ua3.w; L[7] = (short)(ua3.w >> 16);
            *(bf16x8*)&Ah[(tid + 256) * 8] = H;  *(bf16x8*)&Al[(tid + 256) * 8] = L;
        }
        *(float4*)&Bh[tid * 8] = pbh0;  *(float4*)&Bh[(tid + 256) * 8] = pbh1;
        *(float4*)&Bl[tid * 8] = pbl0;  *(float4*)&Bl[(tid + 256) * 8] = pbl1;

        int kn = (k0 + 32) & 1023;
        {
            int c = kn + c8;
            int hh = c >> 6, d = c & 63;
            size_t ia0 = ((size_t)(b0 * NH + hh) * Tt + t0) * 64 + d;
            size_t ia1 = ((size_t)(b1 * NH + hh) * Tt + t1) * 64 + d;
            ua0 = *(const uint4*)(Opk + ia0);  ua1 = *(const uint4*)(Opk + ia0 + 4);
            ua2 = *(const uint4*)(Opk + ia1);  ua3 = *(const uint4*)(Opk + ia1 + 4);
            pbh0 = *(const float4*)(WOhi + gb0 + kn);
            pbh1 = *(const float4*)(WOhi + gb1 + kn);
            pbl0 = *(const float4*)(WOlo + gb0 + kn);
            pbl1 = *(const float4*)(WOlo + gb1 + kn);
        }
        __syncthreads();

        const int fr = l & 15;
        const int fg = (l >> 4) * 8;
        bf16x8 ah[4], alo[4], bhv[4], blo[4];
        #pragma unroll
        for (int m = 0; m < 4; ++m) {
            int ro = (wr * 64 + m * 16 + fr) * 32 + fg;
            ah[m]  = *(const bf16x8*)&Ah[ro];
            alo[m] = *(const bf16x8*)&Al[ro];
        }
        #pragma unroll
        for (int n = 0; n < 4; ++n) {
            int ro = (wc * 64 + n * 16 + fr) * 32 + fg;
            bhv[n] = *(const bf16x8*)&Bh[ro];
            blo[n] = *(const bf16x8*)&Bl[ro];
        }
        #pragma unroll
        for (int m = 0; m < 4; ++m)
            #pragma unroll
            for (int n = 0; n < 4; ++n) {
                acc[m][n] = __builtin_amdgcn_mfma_f32_16x16x32_bf16(ah[m],  bhv[n], acc[m][n], 0, 0, 0);
                acc[m][n] = __builtin_amdgcn_mfma_f32_16x16x32_bf16(ah[m],  blo[n], acc[m][n], 0, 0, 0);
                acc[m][n] = __builtin_amdgcn_mfma_f32_16x16x32_bf16(alo[m], bhv[n], acc[m][n], 0, 0, 0);
            }
    }

    const int fr = l & 15, fq = l >> 4;
    #pragma unroll
    for (int m = 0; m < 4; ++m)
        #pragma unroll
        for (int n = 0; n < 4; ++n) {
            int col = bn + wc * 64 + n * 16 + fr;
            #pragma unroll
            for (int i = 0; i < 4; ++i) {
                int r = bm + wr * 64 + m * 16 + fq * 4 + i;
                Out[(size_t)r * 1024 + col] = acc[m][n][i];
            }
        }
}

// ---------------------------------------------------------------------------
extern "C" void kernel_launch(void* const* d_in, const int* in_sizes, int n_in,
                              void* d_out, int out_size, void* d_ws, size_t ws_size,
                              hipStream_t stream)
{
    const float* x    = (const float*)d_in[0];   // (4, 2048, 1024)
    const float* wqkv = (const float*)d_in[1];   // (3072, 1024)
    const float* wout = (const float*)d_in[2];   // (1024, 1024)
    float* out = (float*)d_out;

    // ws layout (<=113 MB):
    //   [0,32M):   Q fp32  -> later packed O (bf16 hi|lo per uint32, same idx)
    //   [32,64M):  K fp32  [bh][t][d]
    //   [64,96M):  Vt fp32 [bh][d][t]  (TRANSPOSED for MFMA attention)
    //   [96,102M): Wqkv hi   [102,108M): Wqkv lo
    //   [108,110M): Wout hi  [110,112M): Wout lo
    //   [112M,+512K): rope table
    // d_out (32 MB) holds Xhi/Xlo until gemm_out overwrites it.
    char* wsb = (char*)d_ws;
    float*        Qf  = (float*)(wsb);
    unsigned int* Opk = (unsigned int*)(wsb);
    float*        Kf  = (float*)(wsb + (size_t)32  * 1048576);
    float*        Vtf = (float*)(wsb + (size_t)64  * 1048576);
    short*        Whi = (short*)(wsb + (size_t)96  * 1048576);
    short*        Wlo = (short*)(wsb + (size_t)102 * 1048576);
    short*        WOhi= (short*)(wsb + (size_t)108 * 1048576);
    short*        WOlo= (short*)(wsb + (size_t)110 * 1048576);
    float*        tab = (float*)(wsb + (size_t)112 * 1048576);

    short* Xhi = (short*)d_out;
    short* Xlo = (short*)d_out + 8388608;

    rope_table<<<256, 256, 0, stream>>>(tab);
    cast_split<<<8192, 256, 0, stream>>>(x,    Xhi,  Xlo,  2097152);
    cast_split<<<3072, 256, 0, stream>>>(wqkv, Whi,  Wlo,  786432);
    cast_split<<<1024, 256, 0, stream>>>(wout, WOhi, WOlo, 262144);

    dim3 g1(24, 64);
    gemm_qkv_mfma<<<g1, 256, 0, stream>>>(Xhi, Xlo, Whi, Wlo, tab, Qf, Kf, Vtf);

    dim3 g2(32, 64);
    attn_fwd_mfma<<<g2, 256, 0, stream>>>(Qf, Kf, Vtf, Opk);

    dim3 g3(8, 64);
    gemm_out_mfma<<<g3, 256, 0, stream>>>(Opk, WOhi, WOlo, out);
}

// Round 8
// 744.218 us; speedup vs baseline: 23.2487x; 1.0014x over previous
//
#include <hip/hip_runtime.h>
#include <hip/hip_bf16.h>
#include <math.h>

// Problem constants
constexpr int Bb  = 4;
constexpr int Tt  = 2048;
constexpr int DM  = 1024;
constexpr int NH  = 16;
constexpr int HD  = 64;
constexpr int MBT = Bb * Tt;                       // 8192
constexpr float LOG_THETA = 9.210340371976184f;    // ln(10000)

using bf16x8 = __attribute__((ext_vector_type(8))) short;   // 8 bf16 (4 VGPRs)
using f32x4  = __attribute__((ext_vector_type(4))) float;   // MFMA accumulator

__device__ inline short f2bf(float x) {
    __hip_bfloat16 h = __float2bfloat16(x);
    return *reinterpret_cast<short*>(&h);
}
__device__ inline float bf2f(short u) {
    __hip_bfloat16 h;
    *reinterpret_cast<short*>(&h) = u;
    return __bfloat162float(h);
}
__device__ inline unsigned int packbf2(float x) {
    short h  = f2bf(x);
    short lo = f2bf(x - bf2f(h));
    return (unsigned int)(unsigned short)h | ((unsigned int)(unsigned short)lo << 16);
}
// 8 fp32 -> bf16 hi/lo vectors (all indices static after unroll)
__device__ inline void split8(float4 a, float4 b, bf16x8& H, bf16x8& L) {
    float x[8] = {a.x, a.y, a.z, a.w, b.x, b.y, b.z, b.w};
    #pragma unroll
    for (int e = 0; e < 8; ++e) {
        short h = f2bf(x[e]);
        H[e] = h;
        L[e] = f2bf(x[e] - bf2f(h));
    }
}

// ---------------------------------------------------------------------------
// RoPE cos/sin table: tab[t*64 + 2p] = cos(t*theta^(-2p/64)), +1 = sin.
// ---------------------------------------------------------------------------
__global__ __launch_bounds__(256) void rope_table(float* __restrict__ tab)
{
    int i = blockIdx.x * 256 + threadIdx.x;   // 0..65535
    int t = i >> 5, p = i & 31;
    float freq = expf(-(float)(2 * p) * (LOG_THETA / 64.0f));
    float ang  = (float)t * freq;
    tab[t * 64 + 2 * p]     = cosf(ang);
    tab[t * 64 + 2 * p + 1] = sinf(ang);
}

// ---------------------------------------------------------------------------
// fp32 -> bf16 hi/lo split arrays. 4 elems/thread.
// ---------------------------------------------------------------------------
__global__ __launch_bounds__(256) void cast_split(
    const float* __restrict__ src, short* __restrict__ hi,
    short* __restrict__ lo, int n4)
{
    int i = blockIdx.x * 256 + threadIdx.x;
    if (i >= n4) return;
    float4 v = reinterpret_cast<const float4*>(src)[i];
    short h0 = f2bf(v.x), h1 = f2bf(v.y), h2 = f2bf(v.z), h3 = f2bf(v.w);
    short l0 = f2bf(v.x - bf2f(h0));
    short l1 = f2bf(v.y - bf2f(h1));
    short l2 = f2bf(v.z - bf2f(h2));
    short l3 = f2bf(v.w - bf2f(h3));
    reinterpret_cast<short4*>(hi)[i] = make_short4(h0, h1, h2, h3);
    reinterpret_cast<short4*>(lo)[i] = make_short4(l0, l1, l2, l3);
}

// ---------------------------------------------------------------------------
// Kernel 1: QKV GEMM via bf16x3 MFMA (~fp32 precision).
// C[8192,3072] = X * Wqkv^T. 128x128 tile, BK=32, 4 waves (2x2), 4x4 frags.
// Epilogue: RoPE + scatter.
//   Q  -> fp32 [bh][t][64]
//   K  -> bf16 hi/lo arrays Khi/Klo [bh][t][64]   (pre-split for attn)
//   V  -> bf16 hi/lo arrays Vthi/Vtlo [bh][64 d][t]  (TRANSPOSED for attn)
// ---------------------------------------------------------------------------
__global__ __launch_bounds__(256) void gemm_qkv_mfma(
    const short* __restrict__ Xhi, const short* __restrict__ Xlo,
    const short* __restrict__ Whi, const short* __restrict__ Wlo,
    const float* __restrict__ tab,
    float* __restrict__ Qo,
    unsigned short* __restrict__ Khi_g, unsigned short* __restrict__ Klo_g,
    unsigned short* __restrict__ Vthi_g, unsigned short* __restrict__ Vtlo_g)
{
    __shared__ __align__(16) short Ah[4096], Al[4096], Bh[4096], Bl[4096];
    const int tid = threadIdx.x;
    const int bm  = blockIdx.y * 128;
    const int bn  = blockIdx.x * 128;
    const int w   = tid >> 6, l = tid & 63;
    const int wr  = w >> 1,  wc = w & 1;

    const int r0 = tid >> 2;
    const int c0 = (tid & 3) * 8;
    const size_t ga0 = (size_t)(bm + r0) * 1024 + c0;
    const size_t ga1 = (size_t)(bm + r0 + 64) * 1024 + c0;
    const size_t gb0 = (size_t)(bn + r0) * 1024 + c0;
    const size_t gb1 = (size_t)(bn + r0 + 64) * 1024 + c0;

    f32x4 acc[4][4];
    #pragma unroll
    for (int m = 0; m < 4; ++m)
        #pragma unroll
        for (int n = 0; n < 4; ++n) acc[m][n] = (f32x4){0.f, 0.f, 0.f, 0.f};

    float4 pah0 = *(const float4*)(Xhi + ga0);
    float4 pah1 = *(const float4*)(Xhi + ga1);
    float4 pal0 = *(const float4*)(Xlo + ga0);
    float4 pal1 = *(const float4*)(Xlo + ga1);
    float4 pbh0 = *(const float4*)(Whi + gb0);
    float4 pbh1 = *(const float4*)(Whi + gb1);
    float4 pbl0 = *(const float4*)(Wlo + gb0);
    float4 pbl1 = *(const float4*)(Wlo + gb1);

    for (int k0 = 0; k0 < 1024; k0 += 32) {
        __syncthreads();
        *(float4*)&Ah[tid * 8] = pah0;  *(float4*)&Ah[(tid + 256) * 8] = pah1;
        *(float4*)&Al[tid * 8] = pal0;  *(float4*)&Al[(tid + 256) * 8] = pal1;
        *(float4*)&Bh[tid * 8] = pbh0;  *(float4*)&Bh[(tid + 256) * 8] = pbh1;
        *(float4*)&Bl[tid * 8] = pbl0;  *(float4*)&Bl[(tid + 256) * 8] = pbl1;
        int kn = (k0 + 32) & 1023;
        pah0 = *(const float4*)(Xhi + ga0 + kn);
        pah1 = *(const float4*)(Xhi + ga1 + kn);
        pal0 = *(const float4*)(Xlo + ga0 + kn);
        pal1 = *(const float4*)(Xlo + ga1 + kn);
        pbh0 = *(const float4*)(Whi + gb0 + kn);
        pbh1 = *(const float4*)(Whi + gb1 + kn);
        pbl0 = *(const float4*)(Wlo + gb0 + kn);
        pbl1 = *(const float4*)(Wlo + gb1 + kn);
        __syncthreads();

        const int fr = l & 15;
        const int fg = (l >> 4) * 8;
        bf16x8 ah[4], alo[4], bhv[4], blo[4];
        #pragma unroll
        for (int m = 0; m < 4; ++m) {
            int ro = (wr * 64 + m * 16 + fr) * 32 + fg;
            ah[m]  = *(const bf16x8*)&Ah[ro];
            alo[m] = *(const bf16x8*)&Al[ro];
        }
        #pragma unroll
        for (int n = 0; n < 4; ++n) {
            int ro = (wc * 64 + n * 16 + fr) * 32 + fg;
            bhv[n] = *(const bf16x8*)&Bh[ro];
            blo[n] = *(const bf16x8*)&Bl[ro];
        }
        #pragma unroll
        for (int m = 0; m < 4; ++m)
            #pragma unroll
            for (int n = 0; n < 4; ++n) {
                acc[m][n] = __builtin_amdgcn_mfma_f32_16x16x32_bf16(ah[m],  bhv[n], acc[m][n], 0, 0, 0);
                acc[m][n] = __builtin_amdgcn_mfma_f32_16x16x32_bf16(ah[m],  blo[n], acc[m][n], 0, 0, 0);
                acc[m][n] = __builtin_amdgcn_mfma_f32_16x16x32_bf16(alo[m], bhv[n], acc[m][n], 0, 0, 0);
            }
    }

    // Epilogue: C/D layout col = lane&15, row = (lane>>4)*4 + reg (m89).
    const int fr = l & 15, fq = l >> 4;
    #pragma unroll
    for (int m = 0; m < 4; ++m) {
        #pragma unroll
        for (int n = 0; n < 4; ++n) {
            int col  = bn + wc * 64 + n * 16 + fr;
            int sect = col >> 10;          // 0=q 1=k 2=v (wave-uniform)
            int cc   = col & 1023;
            int hh   = cc >> 6, d = cc & 63;
            int de   = d & 62;
            #pragma unroll
            for (int i = 0; i < 4; ++i) {
                int r  = bm + wr * 64 + m * 16 + fq * 4 + i;
                int b_ = r >> 11, t_ = r & 2047;
                float v  = acc[m][n][i];
                float vn = __shfl_xor(v, 1);
                if (sect == 2) {
                    // V transposed + pre-split: Vt[bh][d][t]
                    size_t off = ((size_t)(b_ * NH + hh) * HD + d) * Tt + t_;
                    short h = f2bf(v);
                    Vthi_g[off] = (unsigned short)h;
                    Vtlo_g[off] = (unsigned short)f2bf(v - bf2f(h));
                } else {
                    float2 cssn = *(const float2*)(tab + t_ * 64 + de);
                    float outv = (d & 1) ? (vn * cssn.y + v * cssn.x)
                                         : (v * cssn.x - vn * cssn.y);
                    size_t off = ((size_t)(b_ * NH + hh) * Tt + t_) * HD + d;
                    if (sect == 0) {
                        Qo[off] = outv;
                    } else {
                        short h = f2bf(outv);
                        Khi_g[off] = (unsigned short)h;
                        Klo_g[off] = (unsigned short)f2bf(outv - bf2f(h));
                    }
                }
            }
        }
    }
}

// ---------------------------------------------------------------------------
// Kernel 2: causal flash attention, MFMA bf16-hi/lo x3 (~fp32 precision).
// Grid (T/64, B*H). Block 256 = 4 waves; wave w owns q-rows [qi*64+w*16, +16).
// K/Vt pre-split bf16 hi/lo in global -> staging is a pure uint4 copy into
// XOR-swizzled LDS (byte^=(row&7)<<4). No conversion VALU in the tile loop.
// Softmax: 16-lane-group shfl reduce; P routed via per-wave padded LDS.
// Output packed bf16 hi|lo u32 into the Q buffer (block-exclusive rows).
// ---------------------------------------------------------------------------
__global__ __launch_bounds__(256) void attn_fwd_mfma(
    const float* Q,
    const unsigned short* __restrict__ Khi_g, const unsigned short* __restrict__ Klo_g,
    const unsigned short* __restrict__ Vthi_g, const unsigned short* __restrict__ Vtlo_g,
    unsigned int* Opk)
{
    __shared__ __align__(16) short Khi[4096], Klo[4096], Vthi[4096], Vtlo[4096];
    __shared__ __align__(16) unsigned int Ppk[4][16][68];   // pad 64->68

    const int tid = threadIdx.x;
    const int w   = tid >> 6;
    const int l   = tid & 63;
    const int fr  = l & 15;
    const int hi8 = l >> 4;
    const int bh  = blockIdx.y;
    const int qi  = blockIdx.x;
    const int qbase = qi * 64 + w * 16;

    // ---- Q fragments (scale 1/8 folded in), bf16 hi/lo, 2 k-slabs ----
    bf16x8 qh[2], ql[2];
    {
        const float* qp = Q + ((size_t)bh * Tt + qbase + fr) * HD;
        #pragma unroll
        for (int s = 0; s < 2; ++s) {
            float4 a = *(const float4*)(qp + s * 32 + hi8 * 8);
            float4 b = *(const float4*)(qp + s * 32 + hi8 * 8 + 4);
            a.x *= 0.125f; a.y *= 0.125f; a.z *= 0.125f; a.w *= 0.125f;
            b.x *= 0.125f; b.y *= 0.125f; b.z *= 0.125f; b.w *= 0.125f;
            split8(a, b, qh[s], ql[s]);
        }
    }

    f32x4 acc_o[4];
    #pragma unroll
    for (int n = 0; n < 4; ++n) acc_o[n] = (f32x4){0.f, 0.f, 0.f, 0.f};
    float mreg[4] = {-INFINITY, -INFINITY, -INFINITY, -INFINITY};
    float lreg[4] = {0.f, 0.f, 0.f, 0.f};

    // staging mapping: thread -> (row sr, 16-col chunk sc); pure copies.
    const int sr = tid >> 2;
    const int sc = (tid & 3) * 16;
    const unsigned short* khg = Khi_g  + ((size_t)bh * Tt + sr) * HD + sc;
    const unsigned short* klg = Klo_g  + ((size_t)bh * Tt + sr) * HD + sc;
    const unsigned short* vhg = Vthi_g + ((size_t)bh * HD + sr) * Tt + sc;
    const unsigned short* vlg = Vtlo_g + ((size_t)bh * HD + sr) * Tt + sc;

    for (int ki = 0; ki <= qi; ++ki) {
        __syncthreads();   // previous tile's LDS reads complete
        {
            const size_t ko = (size_t)ki * 64 * HD;
            const size_t vo = (size_t)ki * 64;
            #pragma unroll
            for (int h = 0; h < 2; ++h) {
                int off = (sc * 2 + h * 16) ^ ((sr & 7) << 4);
                *(uint4*)((char*)Khi  + sr * 128 + off) = *(const uint4*)(khg + ko + h * 8);
                *(uint4*)((char*)Klo  + sr * 128 + off) = *(const uint4*)(klg + ko + h * 8);
                *(uint4*)((char*)Vthi + sr * 128 + off) = *(const uint4*)(vhg + vo + h * 8);
                *(uint4*)((char*)Vtlo + sr * 128 + off) = *(const uint4*)(vlg + vo + h * 8);
            }
        }
        __syncthreads();

        // ---- S = Q·K^T (bf16x3): lane holds S[q=hi8*4+i][kcol=n*16+fr] ----
        f32x4 acc_s[4];
        #pragma unroll
        for (int n = 0; n < 4; ++n) acc_s[n] = (f32x4){0.f, 0.f, 0.f, 0.f};
        #pragma unroll
        for (int n = 0; n < 4; ++n) {
            int row = n * 16 + fr;
            const char* kh_ = (const char*)Khi + row * 128;
            const char* kl_ = (const char*)Klo + row * 128;
            #pragma unroll
            for (int s = 0; s < 2; ++s) {
                int off = (s * 64 + hi8 * 16) ^ ((row & 7) << 4);
                bf16x8 kh = *(const bf16x8*)(kh_ + off);
                bf16x8 kl = *(const bf16x8*)(kl_ + off);
                acc_s[n] = __builtin_amdgcn_mfma_f32_16x16x32_bf16(qh[s], kh, acc_s[n], 0, 0, 0);
                acc_s[n] = __builtin_amdgcn_mfma_f32_16x16x32_bf16(qh[s], kl, acc_s[n], 0, 0, 0);
                acc_s[n] = __builtin_amdgcn_mfma_f32_16x16x32_bf16(ql[s], kh, acc_s[n], 0, 0, 0);
            }
        }

        // ---- causal mask (diagonal tile only; branch wave-uniform) ----
        if (ki == qi) {
            #pragma unroll
            for (int n = 0; n < 4; ++n)
                #pragma unroll
                for (int i = 0; i < 4; ++i) {
                    int kc = ki * 64 + n * 16 + fr;
                    int qr = qbase + hi8 * 4 + i;
                    if (kc > qr) acc_s[n][i] = -INFINITY;
                }
        }

        // ---- online softmax (row reduce across the 16 fr-lanes) ----
        float tmax[4], scl[4], ps[4][4];
        #pragma unroll
        for (int i = 0; i < 4; ++i)
            tmax[i] = fmaxf(fmaxf(acc_s[0][i], acc_s[1][i]),
                            fmaxf(acc_s[2][i], acc_s[3][i]));
        #pragma unroll
        for (int i = 0; i < 4; ++i) {
            tmax[i] = fmaxf(tmax[i], __shfl_xor(tmax[i], 1));
            tmax[i] = fmaxf(tmax[i], __shfl_xor(tmax[i], 2));
            tmax[i] = fmaxf(tmax[i], __shfl_xor(tmax[i], 4));
            tmax[i] = fmaxf(tmax[i], __shfl_xor(tmax[i], 8));
        }
        #pragma unroll
        for (int i = 0; i < 4; ++i) {
            float mn = fmaxf(mreg[i], tmax[i]);
            scl[i]  = __expf(mreg[i] - mn);
            mreg[i] = mn;
        }
        #pragma unroll
        for (int n = 0; n < 4; ++n)
            #pragma unroll
            for (int i = 0; i < 4; ++i)
                ps[n][i] = __expf(acc_s[n][i] - mreg[i]);
        #pragma unroll
        for (int i = 0; i < 4; ++i) {
            float r = ps[0][i] + ps[1][i] + ps[2][i] + ps[3][i];
            r += __shfl_xor(r, 1);
            r += __shfl_xor(r, 2);
            r += __shfl_xor(r, 4);
            r += __shfl_xor(r, 8);
            lreg[i] = lreg[i] * scl[i] + r;
        }
        #pragma unroll
        for (int n = 0; n < 4; ++n)
            #pragma unroll
            for (int i = 0; i < 4; ++i)
                acc_o[n][i] *= scl[i];

        // ---- P: C-layout -> A-frag layout via per-wave LDS ----
        #pragma unroll
        for (int n = 0; n < 4; ++n)
            #pragma unroll
            for (int i = 0; i < 4; ++i)
                Ppk[w][hi8 * 4 + i][n * 16 + fr] = packbf2(ps[n][i]);

        bf16x8 pah[2], pal[2];
        #pragma unroll
        for (int s = 0; s < 2; ++s) {
            const unsigned int* pr = &Ppk[w][fr][s * 32 + hi8 * 8];
            uint4 u0 = *(const uint4*)pr;
            uint4 u1 = *(const uint4*)(pr + 4);
            unsigned int uu[8] = {u0.x, u0.y, u0.z, u0.w, u1.x, u1.y, u1.z, u1.w};
            #pragma unroll
            for (int e = 0; e < 8; ++e) {
                pah[s][e] = (short)(uu[e] & 0xffffu);
                pal[s][e] = (short)(uu[e] >> 16);
            }
        }

        // ---- O += P·V (bf16x3), Vt rows = d, k-contiguous ----
        #pragma unroll
        for (int n = 0; n < 4; ++n) {
            int row = n * 16 + fr;
            const char* vh_ = (const char*)Vthi + row * 128;
            const char* vl_ = (const char*)Vtlo + row * 128;
            #pragma unroll
            for (int s = 0; s < 2; ++s) {
                int off = (s * 64 + hi8 * 16) ^ ((row & 7) << 4);
                bf16x8 vh = *(const bf16x8*)(vh_ + off);
                bf16x8 vl = *(const bf16x8*)(vl_ + off);
                acc_o[n] = __builtin_amdgcn_mfma_f32_16x16x32_bf16(pah[s], vh, acc_o[n], 0, 0, 0);
                acc_o[n] = __builtin_amdgcn_mfma_f32_16x16x32_bf16(pah[s], vl, acc_o[n], 0, 0, 0);
                acc_o[n] = __builtin_amdgcn_mfma_f32_16x16x32_bf16(pal[s], vh, acc_o[n], 0, 0, 0);
            }
        }
    }

    // ---- epilogue: O/l, pack bf16 hi|lo, write into Q buffer slot ----
    float invl[4];
    #pragma unroll
    for (int i = 0; i < 4; ++i) invl[i] = 1.0f / lreg[i];
    unsigned int* op = Opk + ((size_t)bh * Tt + qbase) * HD;
    #pragma unroll
    for (int n = 0; n < 4; ++n)
        #pragma unroll
        for (int i = 0; i < 4; ++i)
            op[(size_t)(hi8 * 4 + i) * HD + n * 16 + fr] =
                packbf2(acc_o[n][i] * invl[i]);
}

// ---------------------------------------------------------------------------
// Kernel 3: Out[8192,1024] = O * Wout^T, bf16x3 MFMA. A operand unpacked from
// packed hi|lo uint32 in [B][H][T][64] order.
// ---------------------------------------------------------------------------
__global__ __launch_bounds__(256) void gemm_out_mfma(
    const unsigned int* __restrict__ Opk,
    const short* __restrict__ WOhi, const short* __restrict__ WOlo,
    float* __restrict__ Out)
{
    __shared__ __align__(16) short Ah[4096], Al[4096], Bh[4096], Bl[4096];
    const int tid = threadIdx.x;
    const int bm  = blockIdx.y * 128;
    const int bn  = blockIdx.x * 128;
    const int w   = tid >> 6, l = tid & 63;
    const int wr  = w >> 1,  wc = w & 1;

    const int r0 = tid >> 2;
    const int c8 = (tid & 3) * 8;
    const int rA0 = bm + r0, rA1 = bm + r0 + 64;
    const int b0 = rA0 >> 11, t0 = rA0 & 2047;
    const int b1 = rA1 >> 11, t1 = rA1 & 2047;
    const size_t gb0 = (size_t)(bn + r0) * 1024 + c8;
    const size_t gb1 = (size_t)(bn + r0 + 64) * 1024 + c8;

    f32x4 acc[4][4];
    #pragma unroll
    for (int m = 0; m < 4; ++m)
        #pragma unroll
        for (int n = 0; n < 4; ++n) acc[m][n] = (f32x4){0.f, 0.f, 0.f, 0.f};

    uint4 ua0, ua1, ua2, ua3;
    float4 pbh0, pbh1, pbl0, pbl1;
    {
        int c = c8;
        int hh = c >> 6, d = c & 63;
        size_t ia0 = ((size_t)(b0 * NH + hh) * Tt + t0) * 64 + d;
        size_t ia1 = ((size_t)(b1 * NH + hh) * Tt + t1) * 64 + d;
        ua0 = *(const uint4*)(Opk + ia0);  ua1 = *(const uint4*)(Opk + ia0 + 4);
        ua2 = *(const uint4*)(Opk + ia1);  ua3 = *(const uint4*)(Opk + ia1 + 4);
        pbh0 = *(const float4*)(WOhi + gb0);
        pbh1 = *(const float4*)(WOhi + gb1);
        pbl0 = *(const float4*)(WOlo + gb0);
        pbl1 = *(const float4*)(WOlo + gb1);
    }

    for (int k0 = 0; k0 < 1024; k0 += 32) {
        __syncthreads();
        {
            bf16x8 H, L;
            H[0] = (short)ua0.x; L[0] = (short)(ua0.x >> 16);
            H[1] = (short)ua0.y; L[1] = (short)(ua0.y >> 16);
            H[2] = (short)ua0.z; L[2] = (short)(ua0.z >> 16);
            H[3] = (short)ua0.w; L[3] = (short)(ua0.w >> 16);
            H[4] = (short)ua1.x; L[4] = (short)(ua1.x >> 16);
            H[5] = (short)ua1.y; L[5] = (short)(ua1.y >> 16);
            H[6] = (short)ua1.z; L[6] = (short)(ua1.z >> 16);
            H[7] = (short)ua1.w; L[7] = (short)(ua1.w >> 16);
            *(bf16x8*)&Ah[tid * 8] = H;  *(bf16x8*)&Al[tid * 8] = L;
            H[0] = (short)ua2.x; L[0] = (short)(ua2.x >> 16);
            H[1] = (short)ua2.y; L[1] = (short)(ua2.y >> 16);
            H[2] = (short)ua2.z; L[2] = (short)(ua2.z >> 16);
            H[3] = (short)ua2.w; L[3] = (short)(ua2.w >> 16);
            H[4] = (short)ua3.x; L[4] = (short)(ua3.x >> 16);
            H[5] = (short)ua3.y; L[5] = (short)(ua3.y >> 16);
            H[6] = (short)ua3.z; L[6] = (short)(ua3.z >> 16);
            H[7] = (short)ua3.w; L[7] = (short)(ua3.w >> 16);
            *(bf16x8*)&Ah[(tid + 256) * 8] = H;  *(bf16x8*)&Al[(tid + 256) * 8] = L;
        }
        *(float4*)&Bh[tid * 8] = pbh0;  *(float4*)&Bh[(tid + 256) * 8] = pbh1;
        *(float4*)&Bl[tid * 8] = pbl0;  *(float4*)&Bl[(tid + 256) * 8] = pbl1;

        int kn = (k0 + 32) & 1023;
        {
            int c = kn + c8;
            int hh = c >> 6, d = c & 63;
            size_t ia0 = ((size_t)(b0 * NH + hh) * Tt + t0) * 64 + d;
            size_t ia1 = ((size_t)(b1 * NH + hh) * Tt + t1) * 64 + d;
            ua0 = *(const uint4*)(Opk + ia0);  ua1 = *(const uint4*)(Opk + ia0 + 4);
            ua2 = *(const uint4*)(Opk + ia1);  ua3 = *(const uint4*)(Opk + ia1 + 4);
            pbh0 = *(const float4*)(WOhi + gb0 + kn);
            pbh1 = *(const float4*)(WOhi + gb1 + kn);
            pbl0 = *(const float4*)(WOlo + gb0 + kn);
            pbl1 = *(const float4*)(WOlo + gb1 + kn);
        }
        __syncthreads();

        const int fr = l & 15;
        const int fg = (l >> 4) * 8;
        bf16x8 ah[4], alo[4], bhv[4], blo[4];
        #pragma unroll
        for (int m = 0; m < 4; ++m) {
            int ro = (wr * 64 + m * 16 + fr) * 32 + fg;
            ah[m]  = *(const bf16x8*)&Ah[ro];
            alo[m] = *(const bf16x8*)&Al[ro];
        }
        #pragma unroll
        for (int n = 0; n < 4; ++n) {
            int ro = (wc * 64 + n * 16 + fr) * 32 + fg;
            bhv[n] = *(const bf16x8*)&Bh[ro];
            blo[n] = *(const bf16x8*)&Bl[ro];
        }
        #pragma unroll
        for (int m = 0; m < 4; ++m)
            #pragma unroll
            for (int n = 0; n < 4; ++n) {
                acc[m][n] = __builtin_amdgcn_mfma_f32_16x16x32_bf16(ah[m],  bhv[n], acc[m][n], 0, 0, 0);
                acc[m][n] = __builtin_amdgcn_mfma_f32_16x16x32_bf16(ah[m],  blo[n], acc[m][n], 0, 0, 0);
                acc[m][n] = __builtin_amdgcn_mfma_f32_16x16x32_bf16(alo[m], bhv[n], acc[m][n], 0, 0, 0);
            }
    }

    const int fr = l & 15, fq = l >> 4;
    #pragma unroll
    for (int m = 0; m < 4; ++m)
        #pragma unroll
        for (int n = 0; n < 4; ++n) {
            int col = bn + wc * 64 + n * 16 + fr;
            #pragma unroll
            for (int i = 0; i < 4; ++i) {
                int r = bm + wr * 64 + m * 16 + fq * 4 + i;
                Out[(size_t)r * 1024 + col] = acc[m][n][i];
            }
        }
}

// ---------------------------------------------------------------------------
extern "C" void kernel_launch(void* const* d_in, const int* in_sizes, int n_in,
                              void* d_out, int out_size, void* d_ws, size_t ws_size,
                              hipStream_t stream)
{
    const float* x    = (const float*)d_in[0];   // (4, 2048, 1024)
    const float* wqkv = (const float*)d_in[1];   // (3072, 1024)
    const float* wout = (const float*)d_in[2];   // (1024, 1024)
    float* out = (float*)d_out;

    // ws layout (<=113 MB):
    //   [0,32M):   Q fp32  -> later packed O (bf16 hi|lo per uint32, same idx)
    //   [32,48M):  Khi bf16 [bh][t][d]    [48,64M): Klo
    //   [64,80M):  Vthi bf16 [bh][d][t]   [80,96M): Vtlo
    //   [96,102M): Wqkv hi   [102,108M): Wqkv lo
    //   [108,110M): Wout hi  [110,112M): Wout lo
    //   [112M,+512K): rope table
    // d_out (32 MB) holds Xhi/Xlo until gemm_out overwrites it.
    char* wsb = (char*)d_ws;
    float*          Qf   = (float*)(wsb);
    unsigned int*   Opk  = (unsigned int*)(wsb);
    unsigned short* Khig = (unsigned short*)(wsb + (size_t)32 * 1048576);
    unsigned short* Klog = (unsigned short*)(wsb + (size_t)48 * 1048576);
    unsigned short* Vthig= (unsigned short*)(wsb + (size_t)64 * 1048576);
    unsigned short* Vtlog= (unsigned short*)(wsb + (size_t)80 * 1048576);
    short*          Whi  = (short*)(wsb + (size_t)96  * 1048576);
    short*          Wlo  = (short*)(wsb + (size_t)102 * 1048576);
    short*          WOhi = (short*)(wsb + (size_t)108 * 1048576);
    short*          WOlo = (short*)(wsb + (size_t)110 * 1048576);
    float*          tab  = (float*)(wsb + (size_t)112 * 1048576);

    short* Xhi = (short*)d_out;
    short* Xlo = (short*)d_out + 8388608;

    rope_table<<<256, 256, 0, stream>>>(tab);
    cast_split<<<8192, 256, 0, stream>>>(x,    Xhi,  Xlo,  2097152);
    cast_split<<<3072, 256, 0, stream>>>(wqkv, Whi,  Wlo,  786432);
    cast_split<<<1024, 256, 0, stream>>>(wout, WOhi, WOlo, 262144);

    dim3 g1(24, 64);
    gemm_qkv_mfma<<<g1, 256, 0, stream>>>(Xhi, Xlo, Whi, Wlo, tab, Qf,
                                          Khig, Klog, Vthig, Vtlog);

    dim3 g2(32, 64);
    attn_fwd_mfma<<<g2, 256, 0, stream>>>(Qf, Khig, Klog, Vthig, Vtlog, Opk);

    dim3 g3(8, 64);
    gemm_out_mfma<<<g3, 256, 0, stream>>>(Opk, WOhi, WOlo, out);
}